// Round 10
// baseline (158.393 us; speedup 1.0000x reference)
//
#include <hip/hip_runtime.h>

#define BT    16
#define NN    10242
#define CC    64
#define KK    9
#define NBR_  7
#define OO    64
#define MT    32            // rows (nodes) per block -> LDS 37.4KB -> 4 blocks/CU
#define RS    584           // LDS itp row stride in bf16 (16B-aligned)
#define KT    18            // K tiles of 32

using frag  = __attribute__((ext_vector_type(8))) short;   // 8 bf16 (4 VGPRs)
using f32x4 = __attribute__((ext_vector_type(4))) float;

static __device__ __forceinline__ unsigned short f2bf(float f) {
    union { float f; unsigned u; } v; v.f = f;
    unsigned r = v.u + 0x7fffu + ((v.u >> 16) & 1u);   // RNE
    return (unsigned short)(r >> 16);
}

// packed pair via v_cvt_pk_bf16_f32 (native RNE pack — bit-identical to f2bf)
static __device__ __forceinline__ unsigned pk2(float a, float b) {
    unsigned r;
    asm("v_cvt_pk_bf16_f32 %0, %1, %2" : "=v"(r) : "v"(a), "v"(b));
    return r;
}

// q-permutation shared by producer and weight pack:
//   k in [0,8): q = (k>>2)*256 + c*4 + (k&3);  k==8: q = 512 + c
// wb[((t*4+ct)*64+lane)*8+j] = bf16(w[o][c][k]), q=t*32+(lane>>4)*8+j, o=ct*16+(lane&15)
__global__ void pack_w_kernel(const float* __restrict__ w, unsigned short* __restrict__ wb) {
    int i = blockIdx.x * blockDim.x + threadIdx.x;
    if (i >= KT * 4 * 64 * 8) return;
    int j  = i & 7;
    int l  = (i >> 3) & 63;
    int ct = (i >> 9) & 3;
    int t  = i >> 11;
    int q  = t * 32 + (l >> 4) * 8 + j;
    int o  = ct * 16 + (l & 15);
    int c, k;
    if (q < 512) { c = (q & 255) >> 2; k = (q >> 8) * 4 + (q & 3); }
    else         { c = q - 512;        k = 8; }
    wb[i] = f2bf(w[(o * CC + c) * KK + k]);
}

__global__ __launch_bounds__(256, 4) void sphere_conv_kernel(
    const float* __restrict__ x,      // (BT, N, C)
    const int*   __restrict__ index,  // (N, NBR)
    const float* __restrict__ m,      // (N, NBR, K)
    const unsigned short* __restrict__ wb,  // packed B frags (bf16 bits)
    const float* __restrict__ bias,   // (O,)
    float*       __restrict__ out)    // (BT, N, O)
{
    __shared__ unsigned short itp_s[MT * RS];   // 37376 B -> 4 blocks/CU

    const int tid  = threadIdx.x;
    const int nt   = blockIdx.x;                // n-tile fastest (R6 layout)
    const int bt   = blockIdx.y;
    const int n0   = nt * MT;
    const int w    = tid >> 6;
    const int lane = tid & 63;

    // ---- B fragments: 18 x volatile global_load_dwordx4 -> 72 VGPRs that the
    // compiler CANNOT rematerialize or sink (R4's silent failure mode). Each
    // wave reuses them for BOTH 16-node sub-tiles -> B L2-traffic per node /2.
    // The __syncthreads barrier-drain below completes them before first use.
    frag bfr[KT];
    {
        const unsigned short* wbp = wb;         // SGPR pair base
        #pragma unroll
        for (int t = 0; t < KT; ++t) {
            const unsigned voff = (unsigned)(((t * 4 + w) * 64 + lane) * 16);
            asm volatile("global_load_dwordx4 %0, %1, %2"
                         : "=v"(bfr[t]) : "v"(voff), "s"(wbp));
        }
    }

    // ---------------- Producer: 8 rows/wave (2 chunks of 4), lane = channel --
    {
        const float* xbt = x + (size_t)bt * NN * CC;
        #pragma unroll
        for (int rc = 0; rc < 2; ++rc) {
            int nu[4];
            #pragma unroll
            for (int r = 0; r < 4; ++r) {
                const int n = n0 + w * 8 + rc * 4 + r;
                // clamp (reads stay in-bounds; junk rows never stored) + wave-
                // uniform so index/m go through scalar loads (K$/L2)
                nu[r] = __builtin_amdgcn_readfirstlane(n < NN ? n : (NN - 1));
            }

            float xv[4][NBR_];
            #pragma unroll
            for (int r = 0; r < 4; ++r) {
                const int* ip = index + nu[r] * NBR_;          // SGPR -> s_load
                #pragma unroll
                for (int j = 0; j < NBR_; ++j)
                    xv[r][j] = xbt[(size_t)ip[j] * CC + lane]; // 256B gather
            }

            #pragma unroll
            for (int r = 0; r < 4; ++r) {
                const int ns = w * 8 + rc * 4 + r;
                const float* mp = m + nu[r] * (NBR_ * KK);     // SGPR -> s_load
                float acc[KK];
                #pragma unroll
                for (int k = 0; k < KK; ++k) acc[k] = 0.f;
                #pragma unroll
                for (int j = 0; j < NBR_; ++j)
                    #pragma unroll
                    for (int k = 0; k < KK; ++k)
                        acc[k] = fmaf(xv[r][j], mp[j * KK + k], acc[k]);

                uint2 q0, q1;
                q0.x = pk2(acc[0], acc[1]);
                q0.y = pk2(acc[2], acc[3]);
                q1.x = pk2(acc[4], acc[5]);
                q1.y = pk2(acc[6], acc[7]);
                unsigned short* row = &itp_s[ns * RS];
                *(uint2*)(&row[lane * 4])       = q0;          // 8B, 2-way free
                *(uint2*)(&row[256 + lane * 4]) = q1;
                row[512 + lane] = f2bf(acc[8]);
            }
        }
    }
    __syncthreads();    // full drain: itp visible AND bfr loads complete

    // ------------- Consumer: wave = 16 o-cols x (2 x 16-node sub-tiles) -----
    const int ct   = w;
    const int am   = lane & 15;
    const int half = lane >> 4;
    const int o    = ct * 16 + am;
    const float bo = bias[o];
    const size_t obase = (size_t)bt * NN * OO;

    #pragma unroll
    for (int g = 0; g < 2; ++g) {
        const unsigned short* arow = &itp_s[(g * 16 + am) * RS + half * 8];
        f32x4 cacc = (f32x4){0.f, 0.f, 0.f, 0.f};
        #pragma unroll
        for (int t = 0; t < KT; ++t) {
            const frag a = *(const frag*)(arow + t * 32);   // ds_read_b128
            cacc = __builtin_amdgcn_mfma_f32_16x16x32_bf16(a, bfr[t], cacc, 0, 0, 0);
        }
        // D layout: col = lane&15, row = (lane>>4)*4 + i; all 4 waves store the
        // sub-tile in the same phase -> full 256B out lines
        #pragma unroll
        for (int i = 0; i < 4; ++i) {
            const int n = n0 + g * 16 + half * 4 + i;
            if (n < NN) out[obase + (size_t)n * OO + o] = cacc[i] + bo;
        }
    }
}

extern "C" void kernel_launch(void* const* d_in, const int* in_sizes, int n_in,
                              void* d_out, int out_size, void* d_ws, size_t ws_size,
                              hipStream_t stream) {
    const float* x      = (const float*)d_in[0];
    const int*   index  = (const int*)  d_in[1];
    const float* m      = (const float*)d_in[2];
    const float* conv_w = (const float*)d_in[3];
    const float* conv_b = (const float*)d_in[4];
    float* out = (float*)d_out;
    unsigned short* wb = (unsigned short*)d_ws;   // 73728 B

    {   // pack weights into MFMA B-fragment order
        const int total = KT * 4 * 64 * 8;
        pack_w_kernel<<<(total + 255) / 256, 256, 0, stream>>>(conv_w, wb);
    }
    {   // fused gather + interp + MFMA conv (n-tile fastest)
        dim3 grid((NN + MT - 1) / MT, BT);        // 321 x 16
        sphere_conv_kernel<<<grid, 256, 0, stream>>>(x, index, m, wb, conv_b, out);
    }
}

// Round 11
// 143.568 us; speedup vs baseline: 1.1033x; 1.1033x over previous
//
#include <hip/hip_runtime.h>

#define BT     16
#define NN     10242
#define CC     64
#define KK     9
#define NBR_   7
#define OO     64
#define MT     16            // rows (nodes) per block  -> LDS 18.7KB -> 8 blocks/CU
#define RS     584           // LDS itp row stride in bf16 (16B-aligned)
#define KT     18            // K tiles of 32
#define NTILES 641           // ceil(NN/MT)

using frag  = __attribute__((ext_vector_type(8))) short;   // 8 bf16 (4 VGPRs)
using f32x4 = __attribute__((ext_vector_type(4))) float;

static __device__ __forceinline__ unsigned short f2bf(float f) {
    union { float f; unsigned u; } v; v.f = f;
    unsigned r = v.u + 0x7fffu + ((v.u >> 16) & 1u);   // RNE
    return (unsigned short)(r >> 16);
}

// packed pair via v_cvt_pk_bf16_f32 (native RNE pack — bit-identical to f2bf)
static __device__ __forceinline__ unsigned pk2(float a, float b) {
    unsigned r;
    asm("v_cvt_pk_bf16_f32 %0, %1, %2" : "=v"(r) : "v"(a), "v"(b));
    return r;
}

// q-permutation shared by producer and weight pack:
//   k in [0,8): q = (k>>2)*256 + c*4 + (k&3);  k==8: q = 512 + c
// wb[((t*4+ct)*64+lane)*8+j] = bf16(w[o][c][k]), q=t*32+(lane>>4)*8+j, o=ct*16+(lane&15)
__global__ void pack_w_kernel(const float* __restrict__ w, unsigned short* __restrict__ wb) {
    int i = blockIdx.x * blockDim.x + threadIdx.x;
    if (i >= KT * 4 * 64 * 8) return;
    int j  = i & 7;
    int l  = (i >> 3) & 63;
    int ct = (i >> 9) & 3;
    int t  = i >> 11;
    int q  = t * 32 + (l >> 4) * 8 + j;
    int o  = ct * 16 + (l & 15);
    int c, k;
    if (q < 512) { c = (q & 255) >> 2; k = (q >> 8) * 4 + (q & 3); }
    else         { c = q - 512;        k = 8; }
    wb[i] = f2bf(w[(o * CC + c) * KK + k]);
}

__global__ __launch_bounds__(256, 8) void sphere_conv_kernel(
    const float* __restrict__ x,      // (BT, N, C)
    const int*   __restrict__ index,  // (N, NBR)
    const float* __restrict__ m,      // (N, NBR, K)
    const unsigned short* __restrict__ wb,  // packed B frags (bf16 bits)
    const float* __restrict__ bias,   // (O,)
    float*       __restrict__ out)    // (BT, N, O)
{
    __shared__ unsigned short itp_s[MT * RS];   // 18688 B -> 8 blocks/CU

    const int tid  = threadIdx.x;
    const int w    = tid >> 6;
    const int lane = tid & 63;

    // ---- XCD-ownership swizzle (bijective: 10256 % 8 == 0): XCD c owns bt
    // {2c,2c+1}, sweeps nt in slot order -> concurrent gather working set per
    // XCD = ONE 2.62MB x-slice. Combined with non-temporal out stores (below)
    // the slice fits and stays in the 4MB XCD L2.
    const int bid  = blockIdx.x;               // [0, 8*2*NTILES)
    const int xcd  = bid & 7;
    const int slot = bid >> 3;                 // [0, 2*NTILES)
    const int btl  = slot / NTILES;            // 0 or 1
    const int nt   = slot - btl * NTILES;      // [0, NTILES)
    const int bt   = xcd * 2 + btl;
    const int n0   = nt * MT;

    // ---------------- Producer: 4 rows/wave, lane = channel ------------------
    {
        const float* xbt = x + (size_t)bt * NN * CC;

        int nu[4];
        #pragma unroll
        for (int r = 0; r < 4; ++r) {
            const int n = n0 + w * 4 + r;
            // clamp (reads stay in-bounds; junk rows never stored) + wave-uniform
            // so index/m go through scalar loads (K$/L2)
            nu[r] = __builtin_amdgcn_readfirstlane(n < NN ? n : (NN - 1));
        }

        float xv[4][NBR_];
        #pragma unroll
        for (int r = 0; r < 4; ++r) {
            const int* ip = index + nu[r] * NBR_;          // SGPR base -> s_load
            #pragma unroll
            for (int j = 0; j < NBR_; ++j)
                xv[r][j] = xbt[(size_t)ip[j] * CC + lane]; // coalesced 256B gather
        }

        #pragma unroll
        for (int r = 0; r < 4; ++r) {
            const int ns = w * 4 + r;
            const float* mp = m + nu[r] * (NBR_ * KK);     // SGPR base -> s_load
            float acc[KK];
            #pragma unroll
            for (int k = 0; k < KK; ++k) acc[k] = 0.f;
            #pragma unroll
            for (int j = 0; j < NBR_; ++j)
                #pragma unroll
                for (int k = 0; k < KK; ++k)
                    acc[k] = fmaf(xv[r][j], mp[j * KK + k], acc[k]);

            uint2 q0, q1;
            q0.x = pk2(acc[0], acc[1]);
            q0.y = pk2(acc[2], acc[3]);
            q1.x = pk2(acc[4], acc[5]);
            q1.y = pk2(acc[6], acc[7]);
            unsigned short* row = &itp_s[ns * RS];
            *(uint2*)(&row[lane * 4])       = q0;          // 8B, 2-way banks = free
            *(uint2*)(&row[256 + lane * 4]) = q1;
            row[512 + lane] = f2bf(acc[8]);
        }
    }
    __syncthreads();

    // ------------- Consumer: wave = 16 rows x 16 cols (ct = wave id) --------
    const int ct   = w;
    const int am   = lane & 15;
    const int half = lane >> 4;

    f32x4 cacc = (f32x4){0.f, 0.f, 0.f, 0.f};

    const unsigned short* arow = &itp_s[am * RS + half * 8];
    const frag* wbf = (const frag*)wb;

    #pragma unroll
    for (int t = 0; t < KT; ++t) {
        const frag a = *(const frag*)(arow + t * 32);       // ds_read_b128
        const frag b = wbf[(t * 4 + ct) * 64 + lane];       // L2-hot
        cacc = __builtin_amdgcn_mfma_f32_16x16x32_bf16(a, b, cacc, 0, 0, 0);
    }

    // ---------------- Epilogue: bias + non-temporal store --------------------
    // D layout: col = lane&15, row = (lane>>4)*4 + i. out is never re-read:
    // nt-stores keep the write stream from evicting the x-slice out of L2.
    const size_t obase = (size_t)bt * NN * OO;
    {
        const int o  = ct * 16 + am;
        const float bo = bias[o];
        #pragma unroll
        for (int i = 0; i < 4; ++i) {
            const int n = n0 + half * 4 + i;
            if (n < NN)
                __builtin_nontemporal_store(cacc[i] + bo,
                                            &out[obase + (size_t)n * OO + o]);
        }
    }
}

extern "C" void kernel_launch(void* const* d_in, const int* in_sizes, int n_in,
                              void* d_out, int out_size, void* d_ws, size_t ws_size,
                              hipStream_t stream) {
    const float* x      = (const float*)d_in[0];
    const int*   index  = (const int*)  d_in[1];
    const float* m      = (const float*)d_in[2];
    const float* conv_w = (const float*)d_in[3];
    const float* conv_b = (const float*)d_in[4];
    float* out = (float*)d_out;
    unsigned short* wb = (unsigned short*)d_ws;   // 73728 B

    {   // pack weights into MFMA B-fragment order
        const int total = KT * 4 * 64 * 8;
        pack_w_kernel<<<(total + 255) / 256, 256, 0, stream>>>(conv_w, wb);
    }
    {   // fused gather + interp + MFMA conv; 8 XCDs x 2 bt x 641 nt
        dim3 grid(8 * 2 * NTILES);                // 10256 blocks
        sphere_conv_kernel<<<grid, 256, 0, stream>>>(x, index, m, wb, conv_b, out);
    }
}

// Round 12
// 143.352 us; speedup vs baseline: 1.1049x; 1.0015x over previous
//
#include <hip/hip_runtime.h>

#define BT     16
#define NN     10242
#define CC     64
#define KK     9
#define NBR_   7
#define OO     64
#define MT     16            // rows (nodes) per block  -> LDS 18.7KB -> 8 blocks/CU
#define RS     584           // LDS itp row stride in bf16 (16B-aligned)
#define KT     18            // K tiles of 32
#define NTILES 641           // ceil(NN/MT)

using frag  = __attribute__((ext_vector_type(8))) short;   // 8 bf16 (4 VGPRs)
using f32x4 = __attribute__((ext_vector_type(4))) float;
using f32x2 = __attribute__((ext_vector_type(2))) float;

static __device__ __forceinline__ unsigned short f2bf(float f) {
    union { float f; unsigned u; } v; v.f = f;
    unsigned r = v.u + 0x7fffu + ((v.u >> 16) & 1u);   // RNE
    return (unsigned short)(r >> 16);
}

// packed pair via v_cvt_pk_bf16_f32 (native RNE pack — bit-identical to f2bf)
static __device__ __forceinline__ unsigned pk2(float a, float b) {
    unsigned r;
    asm("v_cvt_pk_bf16_f32 %0, %1, %2" : "=v"(r) : "v"(a), "v"(b));
    return r;
}

// q-permutation shared by producer and weight pack:
//   k in [0,8): q = (k>>2)*256 + c*4 + (k&3);  k==8: q = 512 + c
// wb[((t*4+ct)*64+lane)*8+j] = bf16(w[o][c][k]), q=t*32+(lane>>4)*8+j, o=ct*16+(lane&15)
__global__ void pack_w_kernel(const float* __restrict__ w, unsigned short* __restrict__ wb) {
    int i = blockIdx.x * blockDim.x + threadIdx.x;
    if (i >= KT * 4 * 64 * 8) return;
    int j  = i & 7;
    int l  = (i >> 3) & 63;
    int ct = (i >> 9) & 3;
    int t  = i >> 11;
    int q  = t * 32 + (l >> 4) * 8 + j;
    int o  = ct * 16 + (l & 15);
    int c, k;
    if (q < 512) { c = (q & 255) >> 2; k = (q >> 8) * 4 + (q & 3); }
    else         { c = q - 512;        k = 8; }
    wb[i] = f2bf(w[(o * CC + c) * KK + k]);
}

__global__ __launch_bounds__(256, 8) void sphere_conv_kernel(
    const float* __restrict__ x,      // (BT, N, C)
    const int*   __restrict__ index,  // (N, NBR)
    const float* __restrict__ m,      // (N, NBR, K)
    const unsigned short* __restrict__ wb,  // packed B frags (bf16 bits)
    const float* __restrict__ bias,   // (O,)
    float*       __restrict__ out)    // (BT, N, O)
{
    __shared__ unsigned short itp_s[MT * RS];   // 18688 B -> 8 blocks/CU

    const int tid  = threadIdx.x;
    const int w    = tid >> 6;
    const int lane = tid & 63;

    // ---- XCD-ownership swizzle (bijective: 10256 % 8 == 0): XCD c owns bt
    // {2c,2c+1}, sweeps nt in slot order -> concurrent gather working set per
    // XCD = ONE 2.62MB x-slice; with nt-stores it stays in the 4MB XCD L2.
    // (R11: FETCH 141 -> 68MB)
    const int bid  = blockIdx.x;               // [0, 8*2*NTILES)
    const int xcd  = bid & 7;
    const int slot = bid >> 3;                 // [0, 2*NTILES)
    const int btl  = slot / NTILES;            // 0 or 1
    const int nt   = slot - btl * NTILES;      // [0, NTILES)
    const int bt   = xcd * 2 + btl;
    const int n0   = nt * MT;

    // ---------------- Producer: 4 rows/wave, lane = channel ------------------
    {
        const float* xbt = x + (size_t)bt * NN * CC;

        int nu[4];
        #pragma unroll
        for (int r = 0; r < 4; ++r) {
            const int n = n0 + w * 4 + r;
            // clamp (reads stay in-bounds; junk rows never stored) + wave-uniform
            // so index/m go through scalar loads (K$/L2)
            nu[r] = __builtin_amdgcn_readfirstlane(n < NN ? n : (NN - 1));
        }

        float xv[4][NBR_];
        #pragma unroll
        for (int r = 0; r < 4; ++r) {
            const int* ip = index + nu[r] * NBR_;          // SGPR base -> s_load
            #pragma unroll
            for (int j = 0; j < NBR_; ++j)
                xv[r][j] = xbt[(size_t)ip[j] * CC + lane]; // coalesced 256B gather
        }

        #pragma unroll
        for (int r = 0; r < 4; ++r) {
            const int ns = w * 4 + r;
            const float* mp = m + nu[r] * (NBR_ * KK);     // SGPR base -> s_load

            // Packed-FP32 interp: k-pairs (0,1)(2,3)(4,5)(6,7) in f32x2 accs,
            // v_pk_fma_f32 via elementwise_fma -> 2 FMAs/instr. m-pairs are
            // memory-adjacent (SGPR pair); xv broadcast is 1 v_mov. Same
            // per-k accumulation order -> bit-identical to scalar version.
            f32x2 acc2[4];
            float acc8 = 0.f;
            #pragma unroll
            for (int p = 0; p < 4; ++p) acc2[p] = (f32x2){0.f, 0.f};
            #pragma unroll
            for (int j = 0; j < NBR_; ++j) {
                const float xvj = xv[r][j];
                const f32x2 xv2 = (f32x2){xvj, xvj};
                #pragma unroll
                for (int p = 0; p < 4; ++p) {
                    const f32x2 m2 = (f32x2){mp[j * KK + 2 * p],
                                             mp[j * KK + 2 * p + 1]};
                    acc2[p] = __builtin_elementwise_fma(xv2, m2, acc2[p]);
                }
                acc8 = fmaf(xvj, mp[j * KK + 8], acc8);
            }

            uint2 q0, q1;
            q0.x = pk2(acc2[0][0], acc2[0][1]);
            q0.y = pk2(acc2[1][0], acc2[1][1]);
            q1.x = pk2(acc2[2][0], acc2[2][1]);
            q1.y = pk2(acc2[3][0], acc2[3][1]);
            unsigned short* row = &itp_s[ns * RS];
            *(uint2*)(&row[lane * 4])       = q0;          // 8B, 2-way banks = free
            *(uint2*)(&row[256 + lane * 4]) = q1;
            row[512 + lane] = f2bf(acc8);
        }
    }
    __syncthreads();

    // ------------- Consumer: wave = 16 rows x 16 cols (ct = wave id) --------
    const int ct   = w;
    const int am   = lane & 15;
    const int half = lane >> 4;

    f32x4 cacc = (f32x4){0.f, 0.f, 0.f, 0.f};

    const unsigned short* arow = &itp_s[am * RS + half * 8];
    const frag* wbf = (const frag*)wb;

    #pragma unroll
    for (int t = 0; t < KT; ++t) {
        const frag a = *(const frag*)(arow + t * 32);       // ds_read_b128
        const frag b = wbf[(t * 4 + ct) * 64 + lane];       // L2-hot
        cacc = __builtin_amdgcn_mfma_f32_16x16x32_bf16(a, b, cacc, 0, 0, 0);
    }

    // ---------------- Epilogue: bias + non-temporal store --------------------
    // D layout: col = lane&15, row = (lane>>4)*4 + i. out is never re-read:
    // nt-stores keep the write stream from evicting the x-slice out of L2.
    const size_t obase = (size_t)bt * NN * OO;
    {
        const int o  = ct * 16 + am;
        const float bo = bias[o];
        #pragma unroll
        for (int i = 0; i < 4; ++i) {
            const int n = n0 + half * 4 + i;
            if (n < NN)
                __builtin_nontemporal_store(cacc[i] + bo,
                                            &out[obase + (size_t)n * OO + o]);
        }
    }
}

extern "C" void kernel_launch(void* const* d_in, const int* in_sizes, int n_in,
                              void* d_out, int out_size, void* d_ws, size_t ws_size,
                              hipStream_t stream) {
    const float* x      = (const float*)d_in[0];
    const int*   index  = (const int*)  d_in[1];
    const float* m      = (const float*)d_in[2];
    const float* conv_w = (const float*)d_in[3];
    const float* conv_b = (const float*)d_in[4];
    float* out = (float*)d_out;
    unsigned short* wb = (unsigned short*)d_ws;   // 73728 B

    {   // pack weights into MFMA B-fragment order
        const int total = KT * 4 * 64 * 8;
        pack_w_kernel<<<(total + 255) / 256, 256, 0, stream>>>(conv_w, wb);
    }
    {   // fused gather + interp + MFMA conv; 8 XCDs x 2 bt x 641 nt
        dim3 grid(8 * 2 * NTILES);                // 10256 blocks
        sphere_conv_kernel<<<grid, 256, 0, stream>>>(x, index, m, wb, conv_b, out);
    }
}